// Round 5
// baseline (257.793 us; speedup 1.0000x reference)
//
#include <hip/hip_runtime.h>

typedef __fp16 fp16x2 __attribute__((ext_vector_type(2)));   // cvt_pkrtz result type
typedef _Float16 half8 __attribute__((ext_vector_type(8)));
typedef float floatx4 __attribute__((ext_vector_type(4)));

namespace {

constexpr int NODES = 512;   // nodes per graph
constexpr int DIM   = 256;   // latent dim (floats)
constexpr int BM    = 128;   // block tile (rows and cols)

union Cvt8 { fp16x2 h2[4]; half8 h8; };

__device__ inline half8 pack8(const floatx4 f0, const floatx4 f1) {
  Cvt8 c;
  c.h2[0] = __builtin_amdgcn_cvt_pkrtz(f0.x, f0.y);
  c.h2[1] = __builtin_amdgcn_cvt_pkrtz(f0.z, f0.w);
  c.h2[2] = __builtin_amdgcn_cvt_pkrtz(f1.x, f1.y);
  c.h2[3] = __builtin_amdgcn_cvt_pkrtz(f1.z, f1.w);
  return c.h8;
}

__device__ inline float sigmoidf(float x) {
  return __builtin_amdgcn_rcpf(1.0f + __expf(-x));
}

// ---------- fused kernel: register-direct fragments, NO LDS, NO barriers ----
// C = Z Z^T exactly symmetric -> only tiles tn<=tm: 128 graphs x 10 tiles =
// 1280 blocks, 4 waves, each wave a 64x64 sub-tile via 4x4 mfma 16x16x32_f16.
//
// Key observation: for this MFMA the per-lane A/B fragment is CONTIGUOUS in
// global memory — lane (lrow,quad) of fragment (row-block i, K-step kk) needs
// floats [kk*32 + quad*8 .. +8) of row (base + i*16 + lrow): 32 B = 2 x
// global_load_dwordx4. The 4 quads of a row complete full 128-B lines. So we
// read fragments STRAIGHT FROM L2 (z is XCD-pinned: graph g's 512 KB panel is
// only touched by XCD g%8 and is re-read ~10x from its local L2), convert
// fp32->fp16 in-register, and MFMA. No LDS round-trip, no __syncthreads, no
// vmcnt(0) lockstep: waves free-run, so the compiler hoists step-t+1 loads
// above step-t MFMAs without any schedule surgery, and occupancy rises to
// 3 blocks/CU (VGPR-bound instead of LDS-bound).
// Redundant L2 volume: 512 KB/block, 640 MB total (~18 TB/s demand vs 34.5
// ceiling). HBM unique: ~64 MB read + 134 MB write.
// Diagonal tiles: zA == zB, loads dedup naturally in L1/L2; epilogue skips
// the mirror store. Off-diagonal writes both blocks: (tm,tn) via float4 rows,
// (tn,tm) scalar mirror. Normal stores -> L2 write-combining.
__global__ __launch_bounds__(256, 3)
void fused_kernel(const float* __restrict__ z, float* __restrict__ out) {
  const int bid  = blockIdx.x;
  const int x    = bid & 7;            // XCD
  const int j    = bid >> 3;           // 0..159
  const int ggrp = j / 10;             // 0..15
  const int t    = j - ggrp * 10;      // 0..9, unique tile id
  const int g    = x + 8 * ggrp;       // graph, g%8 == XCD

  int tn, tm;
  if (t < 4)      { tn = 0; tm = t; }
  else if (t < 7) { tn = 1; tm = t - 3; }
  else if (t < 9) { tn = 2; tm = t - 5; }
  else            { tn = 3; tm = 3; }
  const bool diag = (tn == tm);

  const int tid  = threadIdx.x;
  const int lane = tid & 63;
  const int wave = tid >> 6;
  const int wRow = wave >> 1;
  const int wCol = wave & 1;
  const int lrow = lane & 15;
  const int quad = lane >> 4;

  // per-lane fragment base pointers: row = tile_row + i*16 + lrow, col = quad*8
  const float* pA = z + ((size_t)g * NODES + tn * BM + wRow * 64 + lrow) * DIM + quad * 8;
  const float* pB = z + ((size_t)g * NODES + tm * BM + wCol * 64 + lrow) * DIM + quad * 8;

  floatx4 acc[4][4];
#pragma unroll
  for (int i = 0; i < 4; ++i)
#pragma unroll
    for (int jj = 0; jj < 4; ++jj)
      acc[i][jj] = (floatx4){0.f, 0.f, 0.f, 0.f};

  // K loop: 8 steps of K=32. Fully unrolled; per step 16 dwordx4 loads
  // (8 fragments x 32 B/lane), 8 pack8, 16 MFMA. No synchronization at all.
#pragma unroll
  for (int kk = 0; kk < 8; ++kk) {
    const int ko = kk * 32;                       // float offset this K-step
    half8 af[4], bf[4];
#pragma unroll
    for (int i = 0; i < 4; ++i) {
      const float* p = pA + (size_t)i * 16 * DIM + ko;
      const floatx4 a0 = *reinterpret_cast<const floatx4*>(p);
      const floatx4 a1 = *reinterpret_cast<const floatx4*>(p + 4);
      af[i] = pack8(a0, a1);
    }
#pragma unroll
    for (int jj = 0; jj < 4; ++jj) {
      const float* p = pB + (size_t)jj * 16 * DIM + ko;
      const floatx4 b0 = *reinterpret_cast<const floatx4*>(p);
      const floatx4 b1 = *reinterpret_cast<const floatx4*>(p + 4);
      bf[jj] = pack8(b0, b1);
    }
#pragma unroll
    for (int i = 0; i < 4; ++i)
#pragma unroll
      for (int jj = 0; jj < 4; ++jj)
        acc[i][jj] = __builtin_amdgcn_mfma_f32_16x16x32_f16(af[i], bf[jj], acc[i][jj], 0, 0, 0);
  }

  // epilogue: sigmoid once; write block (tm,tn) transposed with float4 rows;
  // off-diagonal also writes the mirror block (tn,tm) with scalar stores.
  // acc[i][j][r] = C[n, m], n = tn*128 + wRow*64 + i*16 + quad*4 + r
  //                         m = tm*128 + wCol*64 + j*16 + lrow
  float* outg = out + (size_t)g * NODES * NODES;
  const int nBase = tn * BM + wRow * 64;
  const int mBase = tm * BM + wCol * 64;
#pragma unroll
  for (int jj = 0; jj < 4; ++jj) {
    const int m = mBase + jj * 16 + lrow;
    float* rowp = outg + (size_t)m * NODES;
#pragma unroll
    for (int i = 0; i < 4; ++i) {
      const int n0 = nBase + i * 16 + quad * 4;
      floatx4 v;
#pragma unroll
      for (int r = 0; r < 4; ++r)
        v[r] = sigmoidf(acc[i][jj][r]);
      *reinterpret_cast<floatx4*>(rowp + n0) = v;          // out[m][n0..n0+3]
      if (!diag) {
#pragma unroll
        for (int r = 0; r < 4; ++r)
          outg[(size_t)(n0 + r) * NODES + m] = v[r];       // out[n][m]
      }
    }
  }
}

} // namespace

extern "C" void kernel_launch(void* const* d_in, const int* in_sizes, int n_in,
                              void* d_out, int out_size, void* d_ws, size_t ws_size,
                              hipStream_t stream) {
  const float* z = (const float*)d_in[0];
  float* out = (float*)d_out;
  (void)d_ws; (void)ws_size;
  hipLaunchKernelGGL(fused_kernel, dim3(128 * 10), dim3(256), 0, stream, z, out);
}

// Round 6
// 245.532 us; speedup vs baseline: 1.0499x; 1.0499x over previous
//
#include <hip/hip_runtime.h>

typedef __fp16 fp16x2 __attribute__((ext_vector_type(2)));   // cvt_pkrtz result type
typedef _Float16 half8 __attribute__((ext_vector_type(8)));
typedef float floatx4 __attribute__((ext_vector_type(4)));

namespace {

constexpr int NODES = 512;   // nodes per graph
constexpr int DIM   = 256;   // latent dim (floats)
constexpr int BM    = 128;   // block tile (rows and cols)

union Cvt8 { fp16x2 h2[4]; half8 h8; };

__device__ inline half8 pack8(const floatx4 f0, const floatx4 f1) {
  Cvt8 c;
  c.h2[0] = __builtin_amdgcn_cvt_pkrtz(f0.x, f0.y);
  c.h2[1] = __builtin_amdgcn_cvt_pkrtz(f0.z, f0.w);
  c.h2[2] = __builtin_amdgcn_cvt_pkrtz(f1.x, f1.y);
  c.h2[3] = __builtin_amdgcn_cvt_pkrtz(f1.z, f1.w);
  return c.h8;
}

__device__ inline float sigmoidf(float x) {
  return __builtin_amdgcn_rcpf(1.0f + __expf(-x));
}

// ---------- fused kernel: register-direct fragments + REGISTER DOUBLE-BUFFER --
// Round-5 counters proved the traffic model (FETCH 35 MB: XCD-local L2 absorbs
// all fragment re-reads) but VGPR_Count=72 proved the compiler kept ZERO loads
// in flight (acc alone is 64 VGPRs) -> 16 serialized L2 latencies per K-step.
// Round-6 fix: explicit two-set register pipeline. Per K-step, issue ALL 16
// loads of step t+1 into the inactive set (X/Y, 64 VGPRs each), then cvt+MFMA
// step t. The cross-phase live ranges force the register allocator to hold 16
// loads in flight; the compiler emits counted vmcnt (never a full drain, no
// barriers exist). launch_bounds(256,2) -> 256-VGPR budget for acc(64)+X(64)
// +Y(64)+frags/addr.
// C = Z Z^T symmetric -> tiles tn<=tm only: 128 graphs x 10 tiles = 1280
// blocks, 4 waves, each wave a 64x64 sub-tile via 4x4 mfma_f32_16x16x32_f16.
// Per-lane A/B fragments are CONTIGUOUS 32 B in global memory (2 x dwordx4).
// Off-diagonal tiles write both output blocks: (tm,tn) float4 rows + (tn,tm)
// scalar mirror. Normal stores -> L2 write-combining.
__global__ __launch_bounds__(256, 2)
void fused_kernel(const float* __restrict__ z, float* __restrict__ out) {
  const int bid  = blockIdx.x;
  const int x    = bid & 7;            // XCD
  const int j    = bid >> 3;           // 0..159
  const int ggrp = j / 10;             // 0..15
  const int t    = j - ggrp * 10;      // 0..9, unique tile id
  const int g    = x + 8 * ggrp;       // graph, g%8 == XCD

  int tn, tm;
  if (t < 4)      { tn = 0; tm = t; }
  else if (t < 7) { tn = 1; tm = t - 3; }
  else if (t < 9) { tn = 2; tm = t - 5; }
  else            { tn = 3; tm = 3; }
  const bool diag = (tn == tm);

  const int tid  = threadIdx.x;
  const int lane = tid & 63;
  const int wave = tid >> 6;
  const int wRow = wave >> 1;
  const int wCol = wave & 1;
  const int lrow = lane & 15;
  const int quad = lane >> 4;

  // per-lane fragment base pointers: row = tile_row + i*16 + lrow, col = quad*8
  const float* pA = z + ((size_t)g * NODES + tn * BM + wRow * 64 + lrow) * DIM + quad * 8;
  const float* pB = z + ((size_t)g * NODES + tm * BM + wCol * 64 + lrow) * DIM + quad * 8;

  floatx4 acc[4][4];
#pragma unroll
  for (int i = 0; i < 4; ++i)
#pragma unroll
    for (int jj = 0; jj < 4; ++jj)
      acc[i][jj] = (floatx4){0.f, 0.f, 0.f, 0.f};

  // two register sets for the fp32 fragment pipeline (64 VGPRs each)
  floatx4 xa0[4], xa1[4], xb0[4], xb1[4];
  floatx4 ya0[4], ya1[4], yb0[4], yb1[4];

  auto loadStep = [&](int ko, floatx4 (&A0)[4], floatx4 (&A1)[4],
                              floatx4 (&B0)[4], floatx4 (&B1)[4]) {
#pragma unroll
    for (int i = 0; i < 4; ++i) {
      const float* p = pA + (size_t)i * 16 * DIM + ko;
      A0[i] = *reinterpret_cast<const floatx4*>(p);
      A1[i] = *reinterpret_cast<const floatx4*>(p + 4);
    }
#pragma unroll
    for (int jj = 0; jj < 4; ++jj) {
      const float* p = pB + (size_t)jj * 16 * DIM + ko;
      B0[jj] = *reinterpret_cast<const floatx4*>(p);
      B1[jj] = *reinterpret_cast<const floatx4*>(p + 4);
    }
  };

  auto computeStep = [&](const floatx4 (&A0)[4], const floatx4 (&A1)[4],
                         const floatx4 (&B0)[4], const floatx4 (&B1)[4]) {
    half8 af[4], bf[4];
#pragma unroll
    for (int i = 0; i < 4; ++i) af[i] = pack8(A0[i], A1[i]);
#pragma unroll
    for (int jj = 0; jj < 4; ++jj) bf[jj] = pack8(B0[jj], B1[jj]);
#pragma unroll
    for (int i = 0; i < 4; ++i)
#pragma unroll
      for (int jj = 0; jj < 4; ++jj)
        acc[i][jj] = __builtin_amdgcn_mfma_f32_16x16x32_f16(af[i], bf[jj], acc[i][jj], 0, 0, 0);
  };

  // software pipeline over 8 K-steps of 32 floats, unrolled in pairs so the
  // X/Y buffer choice is compile-time (rule #20: static indexing only).
  loadStep(0, xa0, xa1, xb0, xb1);
#pragma unroll
  for (int tt = 0; tt < 4; ++tt) {
    loadStep((2 * tt + 1) * 32, ya0, ya1, yb0, yb1);   // prefetch t+1
    computeStep(xa0, xa1, xb0, xb1);                   // compute t (hides it)
    if (tt < 3) loadStep((2 * tt + 2) * 32, xa0, xa1, xb0, xb1);
    computeStep(ya0, ya1, yb0, yb1);
  }

  // epilogue: sigmoid once; write block (tm,tn) transposed with float4 rows;
  // off-diagonal also writes the mirror block (tn,tm) with scalar stores.
  // acc[i][j][r] = C[n, m], n = tn*128 + wRow*64 + i*16 + quad*4 + r
  //                         m = tm*128 + wCol*64 + j*16 + lrow
  float* outg = out + (size_t)g * NODES * NODES;
  const int nBase = tn * BM + wRow * 64;
  const int mBase = tm * BM + wCol * 64;
#pragma unroll
  for (int jj = 0; jj < 4; ++jj) {
    const int m = mBase + jj * 16 + lrow;
    float* rowp = outg + (size_t)m * NODES;
#pragma unroll
    for (int i = 0; i < 4; ++i) {
      const int n0 = nBase + i * 16 + quad * 4;
      floatx4 v;
#pragma unroll
      for (int r = 0; r < 4; ++r)
        v[r] = sigmoidf(acc[i][jj][r]);
      *reinterpret_cast<floatx4*>(rowp + n0) = v;          // out[m][n0..n0+3]
      if (!diag) {
#pragma unroll
        for (int r = 0; r < 4; ++r)
          outg[(size_t)(n0 + r) * NODES + m] = v[r];       // out[n][m]
      }
    }
  }
}

} // namespace

extern "C" void kernel_launch(void* const* d_in, const int* in_sizes, int n_in,
                              void* d_out, int out_size, void* d_ws, size_t ws_size,
                              hipStream_t stream) {
  const float* z = (const float*)d_in[0];
  float* out = (float*)d_out;
  (void)d_ws; (void)ws_size;
  hipLaunchKernelGGL(fused_kernel, dim3(128 * 10), dim3(256), 0, stream, z, out);
}

// Round 7
// 244.381 us; speedup vs baseline: 1.0549x; 1.0047x over previous
//
#include <hip/hip_runtime.h>

typedef __fp16 fp16x2 __attribute__((ext_vector_type(2)));   // cvt_pkrtz result type
typedef _Float16 half8 __attribute__((ext_vector_type(8)));
typedef float floatx4 __attribute__((ext_vector_type(4)));

namespace {

constexpr int NODES = 512;   // nodes per graph
constexpr int DIM   = 256;   // latent dim (floats)
constexpr int BM    = 128;   // block tile (rows and cols)

union Cvt8 { fp16x2 h2[4]; half8 h8; };

__device__ inline half8 pack8(const floatx4 f0, const floatx4 f1) {
  Cvt8 c;
  c.h2[0] = __builtin_amdgcn_cvt_pkrtz(f0.x, f0.y);
  c.h2[1] = __builtin_amdgcn_cvt_pkrtz(f0.z, f0.w);
  c.h2[2] = __builtin_amdgcn_cvt_pkrtz(f1.x, f1.y);
  c.h2[3] = __builtin_amdgcn_cvt_pkrtz(f1.z, f1.w);
  return c.h8;
}

__device__ inline float sigmoidf(float x) {
  return __builtin_amdgcn_rcpf(1.0f + __expf(-x));
}

// ---------- fused kernel: register-direct fragments + PINNED prefetch -------
// Round-6 failure: named X/Y register sets did NOT force loads in flight
// (VGPR stayed 72) — with no memory-ordering construct the scheduler sank
// every global_load down to its use. Round-7 fix: a compiler memory fence
// (asm volatile "" ::: "memory") immediately AFTER each prefetch load-group.
// Memory ops cannot cross the fence, so the 16 loads of step t+1 must ISSUE
// before the (register-only) cvt+MFMA block of step t executes; their results
// stay live across the compute phase -> counted vmcnt, ~16 loads in flight
// per wave, no barrier, no LDS.
//
// Traffic model (verified by round-5/6 counters): FETCH ~35 MB (XCD-pinned
// L2 absorbs all fragment re-reads; graph g lives on XCD g%8), WRITE ~138 MB,
// zero bank conflicts (no LDS at all).
// C = Z Z^T symmetric -> tiles tn<=tm only: 128 graphs x 10 tiles = 1280
// blocks, 4 waves, each wave a 64x64 sub-tile via 4x4 mfma_f32_16x16x32_f16.
// Per-lane A/B fragments are CONTIGUOUS 32 B in global memory (2 x dwordx4;
// the 4 quads of a row complete full 128-B lines).
// Off-diagonal tiles write both output blocks: (tm,tn) float4 rows + (tn,tm)
// scalar mirror. Normal stores -> L2 write-combining.
__global__ __launch_bounds__(256, 2)
void fused_kernel(const float* __restrict__ z, float* __restrict__ out) {
  const int bid  = blockIdx.x;
  const int x    = bid & 7;            // XCD
  const int j    = bid >> 3;           // 0..159
  const int ggrp = j / 10;             // 0..15
  const int t    = j - ggrp * 10;      // 0..9, unique tile id
  const int g    = x + 8 * ggrp;       // graph, g%8 == XCD

  int tn, tm;
  if (t < 4)      { tn = 0; tm = t; }
  else if (t < 7) { tn = 1; tm = t - 3; }
  else if (t < 9) { tn = 2; tm = t - 5; }
  else            { tn = 3; tm = 3; }
  const bool diag = (tn == tm);

  const int tid  = threadIdx.x;
  const int lane = tid & 63;
  const int wave = tid >> 6;
  const int wRow = wave >> 1;
  const int wCol = wave & 1;
  const int lrow = lane & 15;
  const int quad = lane >> 4;

  // per-lane fragment base pointers: row = tile_row + i*16 + lrow, col = quad*8
  const float* pA = z + ((size_t)g * NODES + tn * BM + wRow * 64 + lrow) * DIM + quad * 8;
  const float* pB = z + ((size_t)g * NODES + tm * BM + wCol * 64 + lrow) * DIM + quad * 8;

  floatx4 acc[4][4];
#pragma unroll
  for (int i = 0; i < 4; ++i)
#pragma unroll
    for (int jj = 0; jj < 4; ++jj)
      acc[i][jj] = (floatx4){0.f, 0.f, 0.f, 0.f};

  // two register sets for the fp32 fragment pipeline (64 VGPRs each)
  floatx4 xa0[4], xa1[4], xb0[4], xb1[4];
  floatx4 ya0[4], ya1[4], yb0[4], yb1[4];

  auto loadStep = [&](int ko, floatx4 (&A0)[4], floatx4 (&A1)[4],
                              floatx4 (&B0)[4], floatx4 (&B1)[4]) {
#pragma unroll
    for (int i = 0; i < 4; ++i) {
      const float* p = pA + (size_t)i * 16 * DIM + ko;
      A0[i] = *reinterpret_cast<const floatx4*>(p);
      A1[i] = *reinterpret_cast<const floatx4*>(p + 4);
    }
#pragma unroll
    for (int jj = 0; jj < 4; ++jj) {
      const float* p = pB + (size_t)jj * 16 * DIM + ko;
      B0[jj] = *reinterpret_cast<const floatx4*>(p);
      B1[jj] = *reinterpret_cast<const floatx4*>(p + 4);
    }
    // PIN: loads above may not sink past this point. The following compute
    // phase is register-only, so it still schedules freely; only the load
    // ISSUE order is constrained -> results stay in flight across compute.
    asm volatile("" ::: "memory");
  };

  auto computeStep = [&](const floatx4 (&A0)[4], const floatx4 (&A1)[4],
                         const floatx4 (&B0)[4], const floatx4 (&B1)[4]) {
    half8 af[4], bf[4];
#pragma unroll
    for (int i = 0; i < 4; ++i) af[i] = pack8(A0[i], A1[i]);
#pragma unroll
    for (int jj = 0; jj < 4; ++jj) bf[jj] = pack8(B0[jj], B1[jj]);
#pragma unroll
    for (int i = 0; i < 4; ++i)
#pragma unroll
      for (int jj = 0; jj < 4; ++jj)
        acc[i][jj] = __builtin_amdgcn_mfma_f32_16x16x32_f16(af[i], bf[jj], acc[i][jj], 0, 0, 0);
  };

  // software pipeline over 8 K-steps of 32 floats, unrolled in pairs so the
  // X/Y buffer choice is compile-time (rule #20: static indexing only).
  loadStep(0, xa0, xa1, xb0, xb1);
#pragma unroll
  for (int tt = 0; tt < 4; ++tt) {
    loadStep((2 * tt + 1) * 32, ya0, ya1, yb0, yb1);   // prefetch t+1, pinned
    computeStep(xa0, xa1, xb0, xb1);                   // compute t (hides it)
    if (tt < 3) loadStep((2 * tt + 2) * 32, xa0, xa1, xb0, xb1);
    computeStep(ya0, ya1, yb0, yb1);
  }

  // epilogue: sigmoid once; write block (tm,tn) transposed with float4 rows;
  // off-diagonal also writes the mirror block (tn,tm) with scalar stores.
  // acc[i][j][r] = C[n, m], n = tn*128 + wRow*64 + i*16 + quad*4 + r
  //                         m = tm*128 + wCol*64 + j*16 + lrow
  float* outg = out + (size_t)g * NODES * NODES;
  const int nBase = tn * BM + wRow * 64;
  const int mBase = tm * BM + wCol * 64;
#pragma unroll
  for (int jj = 0; jj < 4; ++jj) {
    const int m = mBase + jj * 16 + lrow;
    float* rowp = outg + (size_t)m * NODES;
#pragma unroll
    for (int i = 0; i < 4; ++i) {
      const int n0 = nBase + i * 16 + quad * 4;
      floatx4 v;
#pragma unroll
      for (int r = 0; r < 4; ++r)
        v[r] = sigmoidf(acc[i][jj][r]);
      *reinterpret_cast<floatx4*>(rowp + n0) = v;          // out[m][n0..n0+3]
      if (!diag) {
#pragma unroll
        for (int r = 0; r < 4; ++r)
          outg[(size_t)(n0 + r) * NODES + m] = v[r];       // out[n][m]
      }
    }
  }
}

} // namespace

extern "C" void kernel_launch(void* const* d_in, const int* in_sizes, int n_in,
                              void* d_out, int out_size, void* d_ws, size_t ws_size,
                              hipStream_t stream) {
  const float* z = (const float*)d_in[0];
  float* out = (float*)d_out;
  (void)d_ws; (void)ws_size;
  hipLaunchKernelGGL(fused_kernel, dim3(128 * 10), dim3(256), 0, stream, z, out);
}

// Round 8
// 231.610 us; speedup vs baseline: 1.1130x; 1.0551x over previous
//
#include <hip/hip_runtime.h>

typedef __fp16 fp16x2 __attribute__((ext_vector_type(2)));   // cvt_pkrtz result type
typedef _Float16 half8 __attribute__((ext_vector_type(8)));
typedef float floatx4 __attribute__((ext_vector_type(4)));

namespace {

constexpr int NODES = 512;   // nodes per graph
constexpr int DIM   = 256;   // latent dim (floats)
constexpr int BM    = 128;   // block tile (rows and cols)

union Cvt8 { fp16x2 h2[4]; half8 h8; };

__device__ inline half8 pack8(const floatx4 f0, const floatx4 f1) {
  Cvt8 c;
  c.h2[0] = __builtin_amdgcn_cvt_pkrtz(f0.x, f0.y);
  c.h2[1] = __builtin_amdgcn_cvt_pkrtz(f0.z, f0.w);
  c.h2[2] = __builtin_amdgcn_cvt_pkrtz(f1.x, f1.y);
  c.h2[3] = __builtin_amdgcn_cvt_pkrtz(f1.z, f1.w);
  return c.h8;
}

__device__ inline float sigmoidf(float x) {
  return __builtin_amdgcn_rcpf(1.0f + __expf(-x));
}

// ---------- fused kernel: register-direct fragments + SCHED_BARRIER pipeline -
// Round-6: named X/Y register sets alone -> scheduler sank loads to uses
// (VGPR 72). Round-7: asm "memory" clobber -> loads pinned, but the
// REGISTER-ONLY compute phase hoisted above them instead (VGPR 68) — rule-#18
// mechanism. Round-8: __builtin_amdgcn_sched_barrier(0) after each load
// group: NOTHING may cross, in either direction. Program order
//   load(t+1) ; SB ; compute(t)
// is now the emitted order; steady state keeps 32 loads outstanding and the
// compiler emits counted vmcnt(16) before each compute (never a drain).
// No LDS, no __syncthreads.
//
// Traffic model (verified rounds 5-7): FETCH ~35 MB (XCD-pinned L2 absorbs
// all fragment re-reads; graph g lives on XCD g%8), WRITE ~135 MB, zero bank
// conflicts. The kernel is latency-bound; this round converts exposed L2
// latency (~300 cy/K-step) into overlapped latency.
//
// C = Z Z^T symmetric -> tiles tn<=tm only: 128 graphs x 10 tiles = 1280
// blocks, 4 waves, each wave a 64x64 sub-tile via 4x4 mfma_f32_16x16x32_f16.
// Per-lane A/B fragments are CONTIGUOUS 32 B in global memory (2 x dwordx4;
// the 4 quads of a row complete full 128-B lines).
// Off-diagonal tiles write both output blocks: (tm,tn) float4 rows + (tn,tm)
// scalar mirror. Normal stores -> L2 write-combining.
__global__ __launch_bounds__(256, 2)
void fused_kernel(const float* __restrict__ z, float* __restrict__ out) {
  const int bid  = blockIdx.x;
  const int x    = bid & 7;            // XCD
  const int j    = bid >> 3;           // 0..159
  const int ggrp = j / 10;             // 0..15
  const int t    = j - ggrp * 10;      // 0..9, unique tile id
  const int g    = x + 8 * ggrp;       // graph, g%8 == XCD

  int tn, tm;
  if (t < 4)      { tn = 0; tm = t; }
  else if (t < 7) { tn = 1; tm = t - 3; }
  else if (t < 9) { tn = 2; tm = t - 5; }
  else            { tn = 3; tm = 3; }
  const bool diag = (tn == tm);

  const int tid  = threadIdx.x;
  const int lane = tid & 63;
  const int wave = tid >> 6;
  const int wRow = wave >> 1;
  const int wCol = wave & 1;
  const int lrow = lane & 15;
  const int quad = lane >> 4;

  // per-lane fragment base pointers: row = tile_row + i*16 + lrow, col = quad*8
  const float* pA = z + ((size_t)g * NODES + tn * BM + wRow * 64 + lrow) * DIM + quad * 8;
  const float* pB = z + ((size_t)g * NODES + tm * BM + wCol * 64 + lrow) * DIM + quad * 8;

  floatx4 acc[4][4];
#pragma unroll
  for (int i = 0; i < 4; ++i)
#pragma unroll
    for (int jj = 0; jj < 4; ++jj)
      acc[i][jj] = (floatx4){0.f, 0.f, 0.f, 0.f};

  // two register sets for the fp32 fragment pipeline (64 VGPRs each)
  floatx4 xa0[4], xa1[4], xb0[4], xb1[4];
  floatx4 ya0[4], ya1[4], yb0[4], yb1[4];

  auto loadStep = [&](int ko, floatx4 (&A0)[4], floatx4 (&A1)[4],
                              floatx4 (&B0)[4], floatx4 (&B1)[4]) {
#pragma unroll
    for (int i = 0; i < 4; ++i) {
      const float* p = pA + (size_t)i * 16 * DIM + ko;
      A0[i] = *reinterpret_cast<const floatx4*>(p);
      A1[i] = *reinterpret_cast<const floatx4*>(p + 4);
    }
#pragma unroll
    for (int jj = 0; jj < 4; ++jj) {
      const float* p = pB + (size_t)jj * 16 * DIM + ko;
      B0[jj] = *reinterpret_cast<const floatx4*>(p);
      B1[jj] = *reinterpret_cast<const floatx4*>(p + 4);
    }
    // HARD scheduling wall: neither the loads above may sink below, nor may
    // any later instruction (incl. register-only cvt/MFMA) hoist above.
    __builtin_amdgcn_sched_barrier(0);
  };

  auto computeStep = [&](const floatx4 (&A0)[4], const floatx4 (&A1)[4],
                         const floatx4 (&B0)[4], const floatx4 (&B1)[4]) {
    half8 af[4], bf[4];
#pragma unroll
    for (int i = 0; i < 4; ++i) af[i] = pack8(A0[i], A1[i]);
#pragma unroll
    for (int jj = 0; jj < 4; ++jj) bf[jj] = pack8(B0[jj], B1[jj]);
#pragma unroll
    for (int i = 0; i < 4; ++i)
#pragma unroll
      for (int jj = 0; jj < 4; ++jj)
        acc[i][jj] = __builtin_amdgcn_mfma_f32_16x16x32_f16(af[i], bf[jj], acc[i][jj], 0, 0, 0);
  };

  // software pipeline over 8 K-steps of 32 floats, unrolled in pairs so the
  // X/Y buffer choice is compile-time (rule #20: static indexing only).
  loadStep(0, xa0, xa1, xb0, xb1);
#pragma unroll
  for (int tt = 0; tt < 4; ++tt) {
    loadStep((2 * tt + 1) * 32, ya0, ya1, yb0, yb1);   // prefetch t+1, pinned
    computeStep(xa0, xa1, xb0, xb1);                   // compute t (hides it)
    if (tt < 3) loadStep((2 * tt + 2) * 32, xa0, xa1, xb0, xb1);
    computeStep(ya0, ya1, yb0, yb1);
  }

  // epilogue: sigmoid once; write block (tm,tn) transposed with float4 rows;
  // off-diagonal also writes the mirror block (tn,tm) with scalar stores.
  // acc[i][j][r] = C[n, m], n = tn*128 + wRow*64 + i*16 + quad*4 + r
  //                         m = tm*128 + wCol*64 + j*16 + lrow
  float* outg = out + (size_t)g * NODES * NODES;
  const int nBase = tn * BM + wRow * 64;
  const int mBase = tm * BM + wCol * 64;
#pragma unroll
  for (int jj = 0; jj < 4; ++jj) {
    const int m = mBase + jj * 16 + lrow;
    float* rowp = outg + (size_t)m * NODES;
#pragma unroll
    for (int i = 0; i < 4; ++i) {
      const int n0 = nBase + i * 16 + quad * 4;
      floatx4 v;
#pragma unroll
      for (int r = 0; r < 4; ++r)
        v[r] = sigmoidf(acc[i][jj][r]);
      *reinterpret_cast<floatx4*>(rowp + n0) = v;          // out[m][n0..n0+3]
      if (!diag) {
#pragma unroll
        for (int r = 0; r < 4; ++r)
          outg[(size_t)(n0 + r) * NODES + m] = v[r];       // out[n][m]
      }
    }
  }
}

} // namespace

extern "C" void kernel_launch(void* const* d_in, const int* in_sizes, int n_in,
                              void* d_out, int out_size, void* d_ws, size_t ws_size,
                              hipStream_t stream) {
  const float* z = (const float*)d_in[0];
  float* out = (float*)d_out;
  (void)d_ws; (void)ws_size;
  hipLaunchKernelGGL(fused_kernel, dim3(128 * 10), dim3(256), 0, stream, z, out);
}

// Round 9
// 214.307 us; speedup vs baseline: 1.2029x; 1.0807x over previous
//
#include <hip/hip_runtime.h>

typedef __fp16 fp16x2 __attribute__((ext_vector_type(2)));   // cvt_pkrtz result type
typedef _Float16 half8 __attribute__((ext_vector_type(8)));
typedef float floatx4 __attribute__((ext_vector_type(4)));

namespace {

constexpr int NODES = 512;   // nodes per graph
constexpr int DIM   = 256;   // latent dim (floats)
constexpr int BM    = 128;   // block tile (rows and cols)
constexpr int BKF   = 32;    // K-step in floats: fp32 row = 128 B = 8 x 16-B chunks
constexpr int PANEL = BM * BKF;   // 4096 floats = 16 KB

union Cvt8 { fp16x2 h2[4]; half8 h8; };

__device__ inline half8 pack8(const floatx4 f0, const floatx4 f1) {
  Cvt8 c;
  c.h2[0] = __builtin_amdgcn_cvt_pkrtz(f0.x, f0.y);
  c.h2[1] = __builtin_amdgcn_cvt_pkrtz(f0.z, f0.w);
  c.h2[2] = __builtin_amdgcn_cvt_pkrtz(f1.x, f1.y);
  c.h2[3] = __builtin_amdgcn_cvt_pkrtz(f1.z, f1.w);
  return c.h8;
}

// async 16-B global -> LDS DMA; LDS dest = wave-uniform base + lane*16
__device__ inline void async_ld16(const void* g, void* lds) {
  __builtin_amdgcn_global_load_lds(
      (const __attribute__((address_space(1))) unsigned int*)g,
      (__attribute__((address_space(3))) unsigned int*)lds,
      16, 0, 0);
}

__device__ inline float sigmoidf(float x) {
  return __builtin_amdgcn_rcpf(1.0f + __expf(-x));
}

// ---------- fused kernel: fp32 LDS staging + OCCUPANCY as the overlap engine -
// Verdict from rounds 5-8: the no-LDS register-direct path plateaus at
// 100-126 us (per-wave load latency exposed, 8 waves/CU can't hide it; four
// scheduling variants bracket it). Round-3's global_load_lds version measured
// ~62 us. Its stall was the vmcnt(0) drain at each __syncthreads with only
// 2 blocks/CU resident. This round keeps that proven DMA structure and
// attacks the drain with OCCUPANCY instead of schedule surgery:
//   BKF 64 -> 32  =>  LDS 64 KB -> 32 KB  =>  4 blocks/CU (16 waves).
// While one block drains at its barrier, three other blocks' MFMA/ds_read/
// stores occupy the CU (m114 mechanism: >=3 blocks/CU of implicit wave-level
// overlap is what explicit pipelining failed to beat). Epilogue store bursts
// likewise overlap other blocks' K-loops.
//
// C = Z Z^T exactly symmetric -> tiles tn<=tm only: 128 graphs x 10 tiles =
// 1280 blocks, 4 waves, each wave 64x64 via 4x4 mfma_f32_16x16x32_f16.
// Graph g pinned to XCD g%8 (bid&7): z panel re-reads dedup in local L2
// (verified rounds 5-8: FETCH ~35 MB).
//
// Staging swizzle (rule 21: linear LDS dest + inverse-swizzled source +
// swizzled read). fp32 row = 128 B = 8 chunks. Bank of [row][chunk] =
// (row*32 + chunk*4) % 32 = chunk*4 -> row-independent: unswizzled reads by
// 16 lanes of the same chunk would be 16-way conflicted. XOR with row&7
// spreads them over 8 chunk slots -> 2 lanes/slot = free (m136).
// Diagonal tiles stage ONE panel (A==B). Off-diagonal write both output
// blocks: (tm,tn) float4 rows + (tn,tm) scalar mirror. Normal stores.
__global__ __launch_bounds__(256, 4)
void fused_kernel(const float* __restrict__ z, float* __restrict__ out) {
  __shared__ __align__(16) float As[PANEL];   // 16 KB
  __shared__ __align__(16) float Bs[PANEL];   // 16 KB

  const int bid  = blockIdx.x;
  const int x    = bid & 7;            // XCD
  const int j    = bid >> 3;           // 0..159
  const int ggrp = j / 10;             // 0..15
  const int t    = j - ggrp * 10;      // 0..9, unique tile id
  const int g    = x + 8 * ggrp;       // graph, g%8 == XCD

  int tn, tm;
  if (t < 4)      { tn = 0; tm = t; }
  else if (t < 7) { tn = 1; tm = t - 3; }
  else if (t < 9) { tn = 2; tm = t - 5; }
  else            { tn = 3; tm = 3; }
  const bool diag = (tn == tm);

  const int tid  = threadIdx.x;
  const int lane = tid & 63;
  const int wave = tid >> 6;
  const int wRow = wave >> 1;
  const int wCol = wave & 1;
  const int lrow = lane & 15;
  const int quad = lane >> 4;

  const float* zA = z + ((size_t)g * NODES + tn * BM) * DIM;
  const float* zB = z + ((size_t)g * NODES + tm * BM) * DIM;

  // staging: 16 insts/panel/K-step (1 KB = 8 rows of 128 B each), 4 per wave.
  // lane -> local row = lane>>3 (0..7), LDS chunk = lane&7; source chunk
  // pre-swizzled cs = (lane&7) ^ (row&7), and row&7 == lane>>3 here.
  const int    sRow = lane >> 3;
  const int    sCs  = (lane & 7) ^ sRow;
  const size_t sOff = (size_t)sRow * DIM + sCs * 4;   // floats

  // fragment-read constants: row = ... + lrow (row&7 == lrow&7); lane needs
  // logical chunks 2*quad, 2*quad+1 -> physical XOR lrow&7.
  const int c0 = (quad * 2)     ^ (lrow & 7);
  const int c1 = (quad * 2 + 1) ^ (lrow & 7);
  const int rA = (wRow * 64 + lrow) * BKF;
  const int rB = (wCol * 64 + lrow) * BKF;

  floatx4 acc[4][4];
#pragma unroll
  for (int i = 0; i < 4; ++i)
#pragma unroll
    for (int jj = 0; jj < 4; ++jj)
      acc[i][jj] = (floatx4){0.f, 0.f, 0.f, 0.f};

  for (int kk = 0; kk < DIM; kk += BKF) {
#pragma unroll
    for (int it = 0; it < 4; ++it) {
      const int q = wave * 4 + it;                   // 0..15, rows q*8..q*8+7
      async_ld16(zA + (size_t)q * 8 * DIM + kk + sOff, &As[q * 256]);
      if (!diag)
        async_ld16(zB + (size_t)q * 8 * DIM + kk + sOff, &Bs[q * 256]);
    }
    __syncthreads();                                 // panel ready (drains)

    const float* pBs = diag ? As : Bs;
    half8 af[4], bf[4];
#pragma unroll
    for (int i = 0; i < 4; ++i) {
      const int base = rA + i * 16 * BKF;
      const floatx4 a0 = *reinterpret_cast<const floatx4*>(&As[base + c0 * 4]);
      const floatx4 a1 = *reinterpret_cast<const floatx4*>(&As[base + c1 * 4]);
      af[i] = pack8(a0, a1);
    }
#pragma unroll
    for (int jj = 0; jj < 4; ++jj) {
      const int base = rB + jj * 16 * BKF;
      const floatx4 b0 = *reinterpret_cast<const floatx4*>(&pBs[base + c0 * 4]);
      const floatx4 b1 = *reinterpret_cast<const floatx4*>(&pBs[base + c1 * 4]);
      bf[jj] = pack8(b0, b1);
    }
#pragma unroll
    for (int i = 0; i < 4; ++i)
#pragma unroll
      for (int jj = 0; jj < 4; ++jj)
        acc[i][jj] = __builtin_amdgcn_mfma_f32_16x16x32_f16(af[i], bf[jj], acc[i][jj], 0, 0, 0);

    __syncthreads();                                 // all reads done before next stage
  }

  // epilogue: sigmoid once; write block (tm,tn) transposed with float4 rows;
  // off-diagonal also writes the mirror block (tn,tm) with scalar stores.
  // acc[i][j][r] = C[n, m], n = tn*128 + wRow*64 + i*16 + quad*4 + r
  //                         m = tm*128 + wCol*64 + j*16 + lrow
  float* outg = out + (size_t)g * NODES * NODES;
  const int nBase = tn * BM + wRow * 64;
  const int mBase = tm * BM + wCol * 64;
#pragma unroll
  for (int jj = 0; jj < 4; ++jj) {
    const int m = mBase + jj * 16 + lrow;
    float* rowp = outg + (size_t)m * NODES;
#pragma unroll
    for (int i = 0; i < 4; ++i) {
      const int n0 = nBase + i * 16 + quad * 4;
      floatx4 v;
#pragma unroll
      for (int r = 0; r < 4; ++r)
        v[r] = sigmoidf(acc[i][jj][r]);
      *reinterpret_cast<floatx4*>(rowp + n0) = v;          // out[m][n0..n0+3]
      if (!diag) {
#pragma unroll
        for (int r = 0; r < 4; ++r)
          outg[(size_t)(n0 + r) * NODES + m] = v[r];       // out[n][m]
      }
    }
  }
}

} // namespace

extern "C" void kernel_launch(void* const* d_in, const int* in_sizes, int n_in,
                              void* d_out, int out_size, void* d_ws, size_t ws_size,
                              hipStream_t stream) {
  const float* z = (const float*)d_in[0];
  float* out = (float*)d_out;
  (void)d_ws; (void)ws_size;
  hipLaunchKernelGGL(fused_kernel, dim3(128 * 10), dim3(256), 0, stream, z, out);
}